// Round 2
// baseline (109.256 us; speedup 1.0000x reference)
//
#include <hip/hip_runtime.h>
#include <hip/hip_bf16.h>

// SubbandCompose R5: coalesced global->LDS staging + persistent cos table.
//
// y[t] = X[0] + (-1)^t X[64] + 2*sum_{m=1..63} X[m] cos(pi*m*t/64), t=0..64.
// With p = min(t,64-t):  E_p = sum_{even m} w_m X[m] cos(pi*m*p/64),
//                        O_p = sum_{odd  m} w_m X[m] cos(pi*m*p/64),
//   y[p] = E_p + O_p,  y[64-p] = E_p - O_p.
// out[s,i,j] = (1/512) * sum_{k=0..5} filt[k*64+j] * y[i+5-k][t(k,j)],
//   t(k,j) = j (k even);  (j==0 ? 64 : 64-j) (k odd).
//
// R5 changes vs R4:
//  (a) A wave's 64 spectrum rows are one contiguous 16.6KB span. Stage it
//      into LDS with 17x global_load_lds dwordx4 (coalesced, linear LDS
//      dest), then extract each lane's row with stride-65 ds_read_b32
//      (odd stride -> bank (l+c)%32, worst 2-way aliasing = free).
//      Replaces 17 per-lane dwordx4 that each touched 64 distinct lines.
//  (b) Ys (bf16) reuses the same LDS region after X is in VGPRs
//      (DS pipe is in-order within a wave; compiler fence added).
//  (c) d_tab persists across launches: build once, early-out after.
//  (d) 2 waves/block (LDS 34.8KB/block -> 4 blocks/CU).

#define NF 65
#define NT 8192
#define TRUE_LEN 8187
#define FPW 59              // output frames per wave (64 rows incl. 5 halo)
#define WPB 139             // waves per batch element: ceil(8187/59)
#define TAB_STRIDE 68       // table row stride (floats)
#define YS_STRIDE 66        // bf16 elems per Ys row (64 rows per wave)
#define XSTG 4352           // staged floats per wave = 17 x 256 (17408 B)

typedef const __attribute__((address_space(4))) float cfloat;
typedef const __attribute__((address_space(1))) void gvoid;
typedef __attribute__((address_space(3))) void lvoid;
typedef float v2f __attribute__((ext_vector_type(2)));

__device__ float d_tab[33 * TAB_STRIDE];
__device__ int d_tab_ready;

__global__ void build_tab_kernel() {
    if (d_tab_ready) return;                 // table persists across launches
    for (int idx = threadIdx.x; idx < 33 * TAB_STRIDE; idx += 256) {
        int p = idx / TAB_STRIDE, n = idx % TAB_STRIDE;
        float v = 0.0f;
        // layout: [0..32] even m=2n; [33] pad; [34..65] odd m=2(n-34)+1
        if (n < 66 && n != 33) {
            int m = (n < 33) ? 2 * n : 2 * (n - 34) + 1;
            float w = (m == 0 || m == 64) ? 1.0f : 2.0f;
            int a = (m * p) & 127;           // cos period 128
            v = w * cospif((float)a * (1.0f / 64.0f));
        }
        d_tab[idx] = v;
    }
    __syncthreads();
    if (threadIdx.x == 0) d_tab_ready = 1;
}

__global__ __launch_bounds__(128)
void subband_main_kernel(const float* __restrict__ g_in,
                         const float* __restrict__ g_filt,
                         float* __restrict__ g_out)
{
    __shared__ __align__(16) float Xs[2][XSTG];   // wave-private regions

    const int tid  = threadIdx.x;
    const int lane = tid & 63;
    const int wv   = tid >> 6;
    const int wg   = blockIdx.x * 2 + wv;     // global wave id, 0..2223
    const int s     = wg / WPB;               // batch element
    const int fbase = (wg % WPB) * FPW;       // first output frame

    // ---- coalesced staging: rows fbase..fbase+63 of batch s -> LDS linear
    const size_t row0_f = ((size_t)s * NT + fbase) * NF;  // window start (floats)
    const size_t base_f = row0_f & ~(size_t)3;            // 16B align down
    const int    delta  = (int)(row0_f - base_f);         // 0..3
    const float* gsrc   = g_in + base_f;
    // last valid 16B-aligned chunk (total floats = 16*8192*65, %4 == 0)
    const float* gend   = g_in + ((size_t)16 * NT * NF - 4);

    float* xs = &Xs[wv][0];
    #pragma unroll
    for (int c = 0; c < 17; ++c) {
        const float* src = gsrc + c * 256 + lane * 4;
        if (src > gend) src = gend;           // tail clamp (results discarded)
        __builtin_amdgcn_global_load_lds((gvoid*)src, (lvoid*)(xs + c * 256),
                                         16, 0, 0);
    }
    asm volatile("s_waitcnt vmcnt(0)" ::: "memory");

    // ---- extract this lane's row (stride-65: odd -> conflict-free b32 reads)
    const int rb = delta + lane * NF;
    float X[NF];
    #pragma unroll
    for (int c = 0; c < NF; ++c) X[c] = xs[rb + c];

    // pack even/odd pairs for v_pk_fma_f32:
    //   Xe[c] = {X[4c], X[4c+2]},  Xo[c] = {X[4c+1], X[4c+3]}
    v2f Xe[17], Xo[16];
    #pragma unroll
    for (int c = 0; c < 16; ++c) {
        Xe[c] = (v2f){X[4 * c + 0], X[4 * c + 2]};
        Xo[c] = (v2f){X[4 * c + 1], X[4 * c + 3]};
    }
    Xe[16] = (v2f){X[64], 0.0f};              // pairs with {cf[32], pad}

    asm volatile("" ::: "memory");            // order LDS reads before Ys writes

    __hip_bfloat16* ys = (__hip_bfloat16*)xs; // reuse dead X region for Ys
    cfloat* ct = (cfloat*)(unsigned long long)(const float*)d_tab;

    // ---- stage 1: p-loop; table streams via scalar pipe, packed FMAs
    for (int p = 0; p < 33; ++p) {
        cfloat* cf = ct + p * TAB_STRIDE;
        v2f aE = (v2f){0.0f, 0.0f}, aO = (v2f){0.0f, 0.0f};
        #pragma unroll
        for (int k = 0; k < 16; ++k) {
            v2f ce, co;
            __builtin_memcpy(&ce, cf + 2 * k, 8);        // {m=4k, m=4k+2}
            __builtin_memcpy(&co, cf + 34 + 2 * k, 8);   // {m=4k+1, m=4k+3}
            aE = __builtin_elementwise_fma(ce, Xe[k], aE);
            aO = __builtin_elementwise_fma(co, Xo[k], aO);
        }
        {   // edge: {cf[32]=w*cos(pi*p), pad} * {X[64], 0}
            v2f ce;
            __builtin_memcpy(&ce, cf + 32, 8);
            aE = __builtin_elementwise_fma(ce, Xe[16], aE);
        }
        const float e = aE.x + aE.y, o = aO.x + aO.y;
        ys[lane * YS_STRIDE + p]      = __float2bfloat16(e + o);
        ys[lane * YS_STRIDE + 64 - p] = __float2bfloat16(e - o);
    }
    // wave-private LDS: DS pipe is in-order within a wave; no barrier needed.

    // ---- stage 2: 6-tap polyphase, rolling window, lane = j
    const int j = lane;
    float fc[6];
    #pragma unroll
    for (int k = 0; k < 6; ++k) fc[k] = g_filt[k * 64 + j] * (1.0f / 512.0f);
    const int te = j;
    const int to = (j == 0) ? 64 : 64 - j;

    float we[6], wo[6];
    #pragma unroll
    for (int r = 0; r < 5; ++r) {
        we[r] = __bfloat162float(ys[r * YS_STRIDE + te]);
        wo[r] = __bfloat162float(ys[r * YS_STRIDE + to]);
    }
    float* dst = g_out + ((size_t)s * TRUE_LEN + fbase) * 64 + j;

    #pragma unroll
    for (int q = 0; q < FPW; ++q) {
        if (fbase + q >= TRUE_LEN) break;
        we[5] = __bfloat162float(ys[(q + 5) * YS_STRIDE + te]);
        wo[5] = __bfloat162float(ys[(q + 5) * YS_STRIDE + to]);
        const float o = fc[0] * we[5] + fc[1] * wo[4] + fc[2] * we[3]
                      + fc[3] * wo[2] + fc[4] * we[1] + fc[5] * wo[0];
        dst[(size_t)q * 64] = o;
        #pragma unroll
        for (int r = 0; r < 5; ++r) { we[r] = we[r + 1]; wo[r] = wo[r + 1]; }
    }
}

extern "C" void kernel_launch(void* const* d_in, const int* in_sizes, int n_in,
                              void* d_out, int out_size, void* d_ws, size_t ws_size,
                              hipStream_t stream) {
    const float* g_in   = (const float*)d_in[0];  // (16,1,8192,65) fp32
    const float* g_filt = (const float*)d_in[1];  // (384,) fp32
    float* g_out = (float*)d_out;                 // (16,1,8187*64) fp32

    build_tab_kernel<<<1, 256, 0, stream>>>();    // no-op after first launch
    // 2224 waves = 1112 blocks x 2 waves
    subband_main_kernel<<<1112, 128, 0, stream>>>(g_in, g_filt, g_out);
}

// Round 3
// 98.841 us; speedup vs baseline: 1.1054x; 1.1054x over previous
//
#include <hip/hip_runtime.h>
#include <hip/hip_bf16.h>

// SubbandCompose R6: R4 structure (proven fastest) + compile-time cos table.
//
// y[t] = X[0] + (-1)^t X[64] + 2*sum_{m=1..63} X[m] cos(pi*m*t/64), t=0..64.
// With p = min(t,64-t):  E_p = sum_{even m} w_m X[m] cos(pi*m*p/64),
//                        O_p = sum_{odd  m} w_m X[m] cos(pi*m*p/64),
//   y[p] = E_p + O_p,  y[64-p] = E_p - O_p.
// out[s,i,j] = (1/512) * sum_{k=0..5} filt[k*64+j] * y[i+5-k][t(k,j)],
//   t(k,j) = j (k even);  (j==0 ? 64 : 64-j) (k odd).
//
// R6 changes vs R5 (post-mortem driven):
//  (a) REVERT the global_load_lds staging (R5 +10us: vmcnt(0) drain + 65
//      ds_read + X[]&Xe/Xo simultaneously live ~doubled reg pressure; the
//      R4 per-lane loads already had a fully-consumed contiguous wave
//      footprint so there was no over-fetch to fix).
//  (b) cos table is constexpr-generated into __constant__ memory (compile-
//      time Taylor cos, range-reduced, float-exact) -> build_tab kernel and
//      its dispatch+gap are gone. Single dispatch total.

#define NF 65
#define NT 8192
#define TRUE_LEN 8187
#define FPW 59              // output frames per wave (64 rows incl. 5 halo)
#define WPB 139             // waves per batch element: ceil(8187/59)
#define TAB_STRIDE 68       // table row stride (floats)
#define YS_STRIDE 66        // bf16 elems per Ys row (64 rows per wave)

typedef const __attribute__((address_space(4))) float cfloat;
typedef float v2f __attribute__((ext_vector_type(2)));

// ---- compile-time cos table ------------------------------------------------
// layout per row p: [0..32] even m=2n; [33] pad; [34..65] odd m=2(n-34)+1;
// [66..67] pad. Entry = w_m * cos(pi*(m*p mod 128)/64), w = 2 except m=0,64.
struct TabT { float v[33 * TAB_STRIDE]; };

constexpr float tab_entry(int p, int n) {
    if (n == 33 || n >= 66) return 0.0f;
    const int m = (n < 33) ? 2 * n : 2 * (n - 34) + 1;
    const double w = (m == 0 || m == 64) ? 1.0 : 2.0;
    int a = (m * p) & 127;                 // cos has period 128 in a
    int sign = 1;
    if (a > 64) a = 128 - a;               // cos(2pi - t) =  cos t
    if (a > 32) { a = 64 - a; sign = -1; } // cos(pi  - t) = -cos t
    const double x = 3.14159265358979323846264338327950288 * (double)a / 64.0;
    const double x2 = x * x;               // x in [0, pi/2]
    double term = 1.0, sum = 1.0;
    for (int i = 1; i <= 10; ++i) { term *= -x2 / (double)((2*i-1)*(2*i)); sum += term; }
    return (float)(sign * w * sum);
}

constexpr TabT make_tab() {
    TabT t{};
    for (int p = 0; p < 33; ++p)
        for (int n = 0; n < TAB_STRIDE; ++n)
            t.v[p * TAB_STRIDE + n] = tab_entry(p, n);
    return t;
}

__constant__ TabT c_tab = make_tab();

// ---------------------------------------------------------------------------

__global__ __launch_bounds__(256)
void subband_main_kernel(const float* __restrict__ g_in,
                         const float* __restrict__ g_filt,
                         float* __restrict__ g_out)
{
    __shared__ __hip_bfloat16 Ys[4][64 * YS_STRIDE];  // wave-private regions

    const int tid  = threadIdx.x;
    const int lane = tid & 63;
    const int wv   = tid >> 6;
    const int wg   = blockIdx.x * 4 + wv;     // global wave id, 0..2223
    const int s     = wg / WPB;               // batch element
    const int fbase = (wg % WPB) * FPW;       // first output frame
    int h = fbase + lane;                     // this lane's spectrum row
    if (h > NT - 1) h = NT - 1;               // clamp (outputs using it are discarded)

    // ---- load this lane's 65-float spectrum row, packed even/odd pairs.
    // dwordx4 c covers X[4c..4c+3] = {even,odd,even,odd}:
    //   Xe[c] = {X[4c], X[4c+2]},  Xo[c] = {X[4c+1], X[4c+3]}
    const float* xr = g_in + ((size_t)s * NT + h) * NF;
    v2f Xe[17], Xo[16];
    #pragma unroll
    for (int c = 0; c < 16; ++c) {
        float t4[4];
        __builtin_memcpy(t4, xr + 4 * c, 16);
        Xe[c] = (v2f){t4[0], t4[2]};
        Xo[c] = (v2f){t4[1], t4[3]};
    }
    Xe[16] = (v2f){xr[64], 0.0f};             // pairs with {cf[32], pad}

    __hip_bfloat16* ys = &Ys[wv][0];
    cfloat* ct = (cfloat*)(unsigned long long)(const float*)c_tab.v;

    // ---- stage 1: p-loop; table streams via scalar pipe, packed FMAs
    for (int p = 0; p < 33; ++p) {
        cfloat* cf = ct + p * TAB_STRIDE;
        v2f aE = (v2f){0.0f, 0.0f}, aO = (v2f){0.0f, 0.0f};
        #pragma unroll
        for (int k = 0; k < 16; ++k) {
            v2f ce, co;
            __builtin_memcpy(&ce, cf + 2 * k, 8);        // {m=4k, m=4k+2}
            __builtin_memcpy(&co, cf + 34 + 2 * k, 8);   // {m=4k+1, m=4k+3}
            aE = __builtin_elementwise_fma(ce, Xe[k], aE);
            aO = __builtin_elementwise_fma(co, Xo[k], aO);
        }
        {   // edge: {cf[32]=w*cos(pi*p), pad} * {X[64], 0}
            v2f ce;
            __builtin_memcpy(&ce, cf + 32, 8);
            aE = __builtin_elementwise_fma(ce, Xe[16], aE);
        }
        const float e = aE.x + aE.y, o = aO.x + aO.y;
        ys[lane * YS_STRIDE + p]      = __float2bfloat16(e + o);
        ys[lane * YS_STRIDE + 64 - p] = __float2bfloat16(e - o);
    }
    // wave-private LDS: DS pipe is in-order within a wave; no barrier needed.

    // ---- stage 2: 6-tap polyphase, rolling window, lane = j
    const int j = lane;
    float fc[6];
    #pragma unroll
    for (int k = 0; k < 6; ++k) fc[k] = g_filt[k * 64 + j] * (1.0f / 512.0f);
    const int te = j;
    const int to = (j == 0) ? 64 : 64 - j;

    float we[6], wo[6];
    #pragma unroll
    for (int r = 0; r < 5; ++r) {
        we[r] = __bfloat162float(ys[r * YS_STRIDE + te]);
        wo[r] = __bfloat162float(ys[r * YS_STRIDE + to]);
    }
    float* dst = g_out + ((size_t)s * TRUE_LEN + fbase) * 64 + j;

    #pragma unroll
    for (int q = 0; q < FPW; ++q) {
        if (fbase + q >= TRUE_LEN) break;
        we[5] = __bfloat162float(ys[(q + 5) * YS_STRIDE + te]);
        wo[5] = __bfloat162float(ys[(q + 5) * YS_STRIDE + to]);
        const float o = fc[0] * we[5] + fc[1] * wo[4] + fc[2] * we[3]
                      + fc[3] * wo[2] + fc[4] * we[1] + fc[5] * wo[0];
        dst[(size_t)q * 64] = o;
        #pragma unroll
        for (int r = 0; r < 5; ++r) { we[r] = we[r + 1]; wo[r] = wo[r + 1]; }
    }
}

extern "C" void kernel_launch(void* const* d_in, const int* in_sizes, int n_in,
                              void* d_out, int out_size, void* d_ws, size_t ws_size,
                              hipStream_t stream) {
    const float* g_in   = (const float*)d_in[0];  // (16,1,8192,65) fp32
    const float* g_filt = (const float*)d_in[1];  // (384,) fp32
    float* g_out = (float*)d_out;                 // (16,1,8187*64) fp32

    // single dispatch: 2224 waves = 556 blocks x 4 waves
    subband_main_kernel<<<556, 256, 0, stream>>>(g_in, g_filt, g_out);
}